// Round 1
// baseline (500.814 us; speedup 1.0000x reference)
//
#include <hip/hip_runtime.h>

typedef unsigned short u16;
typedef unsigned int   u32;
typedef short bfrag8 __attribute__((ext_vector_type(8)));   // 8 bf16 (raw bits) = 4 VGPRs
typedef float facc4  __attribute__((ext_vector_type(4)));   // MFMA accumulator

#define DIM    1024
#define NH     16
#define HD     64
#define BSZ    4
#define SEQ    2048
#define MROWS  (BSZ*SEQ)      /* 8192 */
#define CHUNK  64
#define NCHUNK (SEQ/CHUNK)    /* 32 */
#define BH     (BSZ*NH)       /* 64 */

__device__ __forceinline__ u16 f2bf(float f) {
  u32 u = __builtin_bit_cast(u32, f);
  u32 r = u + 0x7fffu + ((u >> 16) & 1u);   // RNE
  return (u16)(r >> 16);
}
__device__ __forceinline__ float bf2f(u16 b) {
  return __builtin_bit_cast(float, (u32)b << 16);
}

__device__ __forceinline__ void gload_lds16(const void* g, void* l) {
  __builtin_amdgcn_global_load_lds((const __attribute__((address_space(1))) u32*)g,
                                   (__attribute__((address_space(3))) u32*)l, 16, 0, 0);
}

// ---------------- prep kernels ----------------

// fp32 -> bf16, 4 elems/thread
__global__ __launch_bounds__(256) void conv_f32_bf16(const float* __restrict__ in, u16* __restrict__ out) {
  const int i = (blockIdx.x * 256 + threadIdx.x) * 4;
  const float4 v = *(const float4*)(in + i);
  ushort4 o;
  o.x = f2bf(v.x); o.y = f2bf(v.y); o.z = f2bf(v.z); o.w = f2bf(v.w);
  *(ushort4*)(out + i) = o;
}

// Wq' = Wq @ blockdiag(proj), stored TRANSPOSED bf16: wt[(h*64+e)*DIM + i]
__global__ __launch_bounds__(256) void fold_qk(const float* __restrict__ Wq, const float* __restrict__ Wk,
                                               const float* __restrict__ proj, u16* __restrict__ wt) {
  const int i0 = blockIdx.x * 32;
  const int h  = blockIdx.y;
  const int sel = blockIdx.z;           // 0 -> Wq (slot 0), 1 -> Wk (slot 1)
  const float* W = sel ? Wk : Wq;
  u16* out = wt + (size_t)sel * (DIM*DIM);
  __shared__ float sp[64*64];
  __shared__ float sw[32*64];
  const int tid = threadIdx.x;
  for (int idx = tid; idx < 4096; idx += 256) sp[idx] = proj[idx];
  for (int idx = tid; idx < 2048; idx += 256) {
    int r = idx >> 6, c = idx & 63;
    sw[idx] = W[(size_t)(i0 + r)*DIM + h*64 + c];
  }
  __syncthreads();
  const int i  = tid >> 3;
  const int e0 = (tid & 7) * 8;
  #pragma unroll
  for (int ee = 0; ee < 8; ++ee) {
    const int e = e0 + ee;
    float acc = 0.f;
    for (int d = 0; d < 64; ++d) acc += sw[i*64 + d] * sp[d*64 + e];
    out[(size_t)(h*64 + e)*DIM + i0 + i] = f2bf(acc);
  }
}

// transpose + convert: slot2 = Wv^T, slot3 = Wo^T
__global__ __launch_bounds__(256) void trans_conv(const float* __restrict__ Wv, const float* __restrict__ Wo,
                                                  u16* __restrict__ wt) {
  const int sel = blockIdx.z;
  const float* in = sel ? Wo : Wv;
  u16* out = wt + (size_t)(2 + sel) * (DIM*DIM);
  const int n0 = blockIdx.x * 32, k0 = blockIdx.y * 32;
  __shared__ float tile[32][33];
  const int tid = threadIdx.x;
  for (int idx = tid; idx < 1024; idx += 256) {
    int r = idx >> 5, c = idx & 31;
    tile[r][c] = in[(size_t)(k0 + r)*DIM + n0 + c];
  }
  __syncthreads();
  for (int idx = tid; idx < 1024; idx += 256) {
    int r = idx >> 5, c = idx & 31;
    out[(size_t)(n0 + r)*DIM + k0 + c] = f2bf(tile[c][r]);
  }
}

// ---------------- bf16 MFMA GEMM, C = A @ Bt^T  (Bt is N x K row-major) ----------------
// MODE 0: QKV fused (blockIdx.y selects weight; elu+1 epilogue for q,k; bf16 out)
// MODE 1: final (fp32 out)
template<int MODE>
__global__ __launch_bounds__(256)
void gemm_bt(const u16* __restrict__ A, const u16* __restrict__ W,
             u16* __restrict__ outb, float* __restrict__ outf) {
  __shared__ u16 lA[128*32];
  __shared__ u16 lB[128*32];
  const int tid  = threadIdx.x;
  const int wave = tid >> 6, lane = tid & 63;
  const int wm = wave >> 1, wn = wave & 1;
  const int lr = lane & 15, g = lane >> 4;

  const int m0 = blockIdx.x * 128;
  int sel, ny;
  const u16* Bt;
  if (MODE == 0) { sel = blockIdx.y >> 3; ny = blockIdx.y & 7; Bt = W + (size_t)sel * (DIM*DIM); }
  else           { sel = 0;              ny = blockIdx.y;      Bt = W; }
  const int n0 = ny * 128;

  facc4 acc[4][4] = {};

  for (int kt = 0; kt < DIM; kt += 32) {
    // stage A,B tiles: [128 rows][32 k] bf16, linear LDS, swizzled global column-group
    #pragma unroll
    for (int c = 0; c < 2; ++c) {
      const int slot = c*256 + wave*64 + lane;     // 512 slots of 16B per tile
      const int row  = slot >> 2, cg = slot & 3;
      const int col  = ((cg ^ (row & 3)) << 3);    // pre-swizzled source column
      gload_lds16(A  + (size_t)(m0 + row)*DIM + kt + col, &lA[(c*256 + wave*64)*8]);
      gload_lds16(Bt + (size_t)(n0 + row)*DIM + kt + col, &lB[(c*256 + wave*64)*8]);
    }
    __syncthreads();   // drains vmcnt before barrier
    bfrag8 af[4], bf[4];
    #pragma unroll
    for (int i = 0; i < 4; ++i) {
      const int ar = wm*64 + i*16 + lr;
      af[i] = *(const bfrag8*)&lA[ar*32 + ((g ^ (ar & 3)) << 3)];
      const int br = wn*64 + i*16 + lr;
      bf[i] = *(const bfrag8*)&lB[br*32 + ((g ^ (br & 3)) << 3)];
    }
    #pragma unroll
    for (int i = 0; i < 4; ++i)
      #pragma unroll
      for (int j = 0; j < 4; ++j)
        acc[i][j] = __builtin_amdgcn_mfma_f32_16x16x32_bf16(af[i], bf[j], acc[i][j], 0, 0, 0);
    __syncthreads();
  }

  const bool doElu = (MODE == 0) && (sel < 2);
  #pragma unroll
  for (int i = 0; i < 4; ++i) {
    #pragma unroll
    for (int j = 0; j < 4; ++j) {
      #pragma unroll
      for (int r = 0; r < 4; ++r) {
        const int gm = m0 + wm*64 + i*16 + g*4 + r;   // D: row=(lane>>4)*4+reg
        const int gn = n0 + wn*64 + j*16 + lr;        //    col=lane&15
        float v = acc[i][j][r];
        if (MODE == 0) {
          if (doElu) v = (v > 0.f) ? (v + 1.f) : __expf(v);   // elu(v)+1
          outb[(size_t)sel*((size_t)MROWS*DIM) + (size_t)gm*DIM + gn] = f2bf(v);
        } else {
          outf[(size_t)gm*DIM + gn] = v;
        }
      }
    }
  }
}

// ---------------- chunked causal linear-attention scan (fp32) ----------------

// Phase A: per (b,h,chunk): Ast = K^T V (64x64, d-major), ksum = sum_t k
__global__ __launch_bounds__(256) void phaseA(const u16* __restrict__ Kb, const u16* __restrict__ Vb,
                                              float* __restrict__ Ast, float* __restrict__ ksum) {
  const int c = blockIdx.x, bh = blockIdx.y;
  const int b = bh >> 4, h = bh & 15;
  const int tid = threadIdx.x;
  __shared__ float lK[64*64];
  __shared__ float lV[64*64];
  const size_t mbase = (size_t)b*SEQ + (size_t)c*CHUNK;
  for (int idx = tid; idx < 4096; idx += 256) {
    const int tt = idx >> 6, d = idx & 63;
    lK[idx] = bf2f(Kb[(mbase + tt)*DIM + h*64 + d]);
    lV[idx] = bf2f(Vb[(mbase + tt)*DIM + h*64 + d]);
  }
  __syncthreads();
  const int e = tid & 63, dg = tid >> 6;
  float acc[16] = {};
  for (int tt = 0; tt < 64; ++tt) {
    const float v = lV[tt*64 + e];
    #pragma unroll
    for (int dd = 0; dd < 16; ++dd) acc[dd] += lK[tt*64 + dg*16 + dd] * v;
  }
  float* dst = Ast + ((size_t)(bh*NCHUNK + c) << 12);
  #pragma unroll
  for (int dd = 0; dd < 16; ++dd) dst[(dg*16 + dd)*64 + e] = acc[dd];
  if (dg == 0) {
    float s = 0.f;
    for (int tt = 0; tt < 64; ++tt) s += lK[tt*64 + e];
    ksum[((size_t)bh*NCHUNK + c)*64 + e] = s;
  }
}

// Phase B: in-place EXCLUSIVE prefix over chunks, per (b,h)
__global__ __launch_bounds__(256) void phaseB(float* __restrict__ Ast, float* __restrict__ ksum) {
  const int bh = blockIdx.x;
  const int tid = threadIdx.x;
  float run[16];
  #pragma unroll
  for (int j = 0; j < 16; ++j) run[j] = 0.f;
  float* base = Ast + ((size_t)bh*NCHUNK) * 4096;
  for (int c = 0; c < NCHUNK; ++c) {
    float* p = base + (size_t)c*4096;
    #pragma unroll
    for (int j = 0; j < 16; ++j) {
      const int idx = j*256 + tid;
      const float t = p[idx];
      p[idx] = run[j];
      run[j] += t;
    }
  }
  if (tid < 64) {
    float rs = 0.f;
    float* kp = ksum + (size_t)bh*NCHUNK*64;
    for (int c = 0; c < NCHUNK; ++c) { const float t = kp[c*64 + tid]; kp[c*64 + tid] = rs; rs += t; }
  }
}

// Phase C: out = (Q @ KV_prefix + mask(QK^T) @ V) / (Q . ksum_prefix + rowsum(mask(QK^T)) + eps)
__global__ __launch_bounds__(256) void phaseC(const u16* __restrict__ Qb, const u16* __restrict__ Kb,
                                              const u16* __restrict__ Vb, const float* __restrict__ Ast,
                                              const float* __restrict__ ksum, u16* __restrict__ Ob) {
  const int c = blockIdx.x, bh = blockIdx.y;
  const int b = bh >> 4, h = bh & 15;
  const int tid = threadIdx.x;
  __shared__ float lQ [64*65];
  __shared__ float lKV[64*65];   // holds K first, then prefix KV state
  __shared__ float lV [64*65];
  __shared__ float lP [64*65];
  __shared__ float lden[64];
  __shared__ float lks[64];
  const size_t mbase = (size_t)b*SEQ + (size_t)c*CHUNK;
  for (int idx = tid; idx < 4096; idx += 256) {
    const int r = idx >> 6, d = idx & 63;
    lQ [r*65 + d] = bf2f(Qb[(mbase + r)*DIM + h*64 + d]);
    lKV[r*65 + d] = bf2f(Kb[(mbase + r)*DIM + h*64 + d]);
    lV [r*65 + d] = bf2f(Vb[(mbase + r)*DIM + h*64 + d]);
  }
  if (tid < 64) lks[tid] = ksum[((size_t)bh*NCHUNK + c)*64 + tid];
  __syncthreads();
  {
    const int r = tid >> 2, c0 = (tid & 3) * 16;
    float rs = 0.f;
    for (int cc = c0; cc < c0 + 16; ++cc) {
      float p = 0.f;
      if (cc <= r) {
        for (int d = 0; d < 64; ++d) p += lQ[r*65 + d] * lKV[cc*65 + d];
        rs += p;
      }
      lP[r*65 + cc] = p;
    }
    float rs2 = rs + __shfl_xor(rs, 1, 64);
    rs2 += __shfl_xor(rs2, 2, 64);
    if ((tid & 3) == 0) {
      float qk = 0.f;
      for (int d = 0; d < 64; ++d) qk += lQ[r*65 + d] * lks[d];
      lden[r] = rs2 + qk + 1e-6f;
    }
  }
  __syncthreads();
  {
    const float* kvsrc = Ast + ((size_t)(bh*NCHUNK + c) << 12);
    for (int idx = tid; idx < 4096; idx += 256) {
      const int d = idx >> 6, e = idx & 63;
      lKV[d*65 + e] = kvsrc[idx];
    }
  }
  __syncthreads();
  const int e = tid & 63, rg = tid >> 6;
  for (int r = rg*16; r < rg*16 + 16; ++r) {
    float acc = 0.f;
    for (int d = 0; d < 64; ++d)  acc += lQ[r*65 + d] * lKV[d*65 + e];
    for (int cc = 0; cc < 64; ++cc) acc += lP[r*65 + cc] * lV[cc*65 + e];
    Ob[(mbase + r)*DIM + h*64 + e] = f2bf(acc / lden[r]);
  }
}

// ---------------- launch ----------------
extern "C" void kernel_launch(void* const* d_in, const int* in_sizes, int n_in,
                              void* d_out, int out_size, void* d_ws, size_t ws_size,
                              hipStream_t stream) {
  const float* x    = (const float*)d_in[0];
  const float* Wq   = (const float*)d_in[1];
  const float* Wk   = (const float*)d_in[2];
  const float* Wv   = (const float*)d_in[3];
  const float* Wo   = (const float*)d_in[4];
  const float* proj = (const float*)d_in[5];
  float* out = (float*)d_out;

  char* ws = (char*)d_ws;
  u16*   xb   = (u16*)  (ws);                       // 16,777,216 B : x in bf16
  u16*   wt   = (u16*)  (ws + 16777216);            //  8,388,608 B : Wq',Wk',Wv^T,Wo^T bf16 (transposed)
  u16*   qkv  = (u16*)  (ws + 25165824);            // 50,331,648 B : Q,K,V bf16 (post feature map)
  u16*   Ob   = (u16*)  (ws + 75497472);            // 16,777,216 B : attention out bf16
  float* Ast  = (float*)(ws + 92274688);            // 33,554,432 B : chunk KV states
  float* ksum = (float*)(ws + 125829120);           //    524,288 B : chunk k-sums
  (void)ws_size; (void)in_sizes; (void)n_in; (void)out_size;

  conv_f32_bf16<<<dim3((MROWS*DIM)/1024), 256, 0, stream>>>(x, xb);
  fold_qk      <<<dim3(DIM/32, NH, 2), 256, 0, stream>>>(Wq, Wk, proj, wt);
  trans_conv   <<<dim3(DIM/32, DIM/32, 2), 256, 0, stream>>>(Wv, Wo, wt);

  gemm_bt<0><<<dim3(MROWS/128, 24), 256, 0, stream>>>(xb, wt, qkv, nullptr);

  phaseA<<<dim3(NCHUNK, BH), 256, 0, stream>>>(qkv + (size_t)MROWS*DIM, qkv + 2*(size_t)MROWS*DIM, Ast, ksum);
  phaseB<<<dim3(BH), 256, 0, stream>>>(Ast, ksum);
  phaseC<<<dim3(NCHUNK, BH), 256, 0, stream>>>(qkv, qkv + (size_t)MROWS*DIM, qkv + 2*(size_t)MROWS*DIM,
                                               Ast, ksum, Ob);

  gemm_bt<1><<<dim3(MROWS/128, 8), 256, 0, stream>>>(Ob, wt + 3*(size_t)DIM*DIM, nullptr, out);
}

// Round 2
// 202.492 us; speedup vs baseline: 2.4732x; 2.4732x over previous
//
#include <hip/hip_runtime.h>

typedef unsigned short u16;
typedef unsigned int   u32;
typedef short bfrag8 __attribute__((ext_vector_type(8)));   // 8 bf16 (raw bits) = 4 VGPRs
typedef float facc4  __attribute__((ext_vector_type(4)));   // MFMA accumulator

#define DIM    1024
#define NH     16
#define HD     64
#define BSZ    4
#define SEQ    2048
#define MROWS  (BSZ*SEQ)      /* 8192 */
#define CHUNK  64
#define NCHUNK (SEQ/CHUNK)    /* 32 */
#define BH     (BSZ*NH)       /* 64 */
#define TS     72             /* transposed-tile LDS row stride (u16) — conflict-free b128 frags */

__device__ __forceinline__ u16 f2bf(float f) {
  u32 u = __builtin_bit_cast(u32, f);
  u32 r = u + 0x7fffu + ((u >> 16) & 1u);   // RNE
  return (u16)(r >> 16);
}
__device__ __forceinline__ float bf2f(u16 b) {
  return __builtin_bit_cast(float, (u32)b << 16);
}

__device__ __forceinline__ void gload_lds16(const void* g, void* l) {
  __builtin_amdgcn_global_load_lds((const __attribute__((address_space(1))) u32*)g,
                                   (__attribute__((address_space(3))) u32*)l, 16, 0, 0);
}

// ---------------- prep kernels ----------------

__global__ __launch_bounds__(256) void conv_f32_bf16(const float* __restrict__ in, u16* __restrict__ out) {
  const int i = (blockIdx.x * 256 + threadIdx.x) * 4;
  const float4 v = *(const float4*)(in + i);
  ushort4 o;
  o.x = f2bf(v.x); o.y = f2bf(v.y); o.z = f2bf(v.z); o.w = f2bf(v.w);
  *(ushort4*)(out + i) = o;
}

// Wq' = Wq @ blockdiag(proj), stored TRANSPOSED bf16: wt[(h*64+e)*DIM + i]
__global__ __launch_bounds__(256) void fold_qk(const float* __restrict__ Wq, const float* __restrict__ Wk,
                                               const float* __restrict__ proj, u16* __restrict__ wt) {
  const int i0 = blockIdx.x * 32;
  const int h  = blockIdx.y;
  const int sel = blockIdx.z;           // 0 -> Wq (slot 0), 1 -> Wk (slot 1)
  const float* W = sel ? Wk : Wq;
  u16* out = wt + (size_t)sel * (DIM*DIM);
  __shared__ float sp[64*64];
  __shared__ float sw[32*64];
  const int tid = threadIdx.x;
  for (int idx = tid; idx < 4096; idx += 256) sp[idx] = proj[idx];
  for (int idx = tid; idx < 2048; idx += 256) {
    int r = idx >> 6, c = idx & 63;
    sw[idx] = W[(size_t)(i0 + r)*DIM + h*64 + c];
  }
  __syncthreads();
  const int i  = tid >> 3;
  const int e0 = (tid & 7) * 8;
  #pragma unroll
  for (int ee = 0; ee < 8; ++ee) {
    const int e = e0 + ee;
    float acc = 0.f;
    for (int d = 0; d < 64; ++d) acc += sw[i*64 + d] * sp[d*64 + e];
    out[(size_t)(h*64 + e)*DIM + i0 + i] = f2bf(acc);
  }
}

// transpose + convert: slot2 = Wv^T, slot3 = Wo^T
__global__ __launch_bounds__(256) void trans_conv(const float* __restrict__ Wv, const float* __restrict__ Wo,
                                                  u16* __restrict__ wt) {
  const int sel = blockIdx.z;
  const float* in = sel ? Wo : Wv;
  u16* out = wt + (size_t)(2 + sel) * (DIM*DIM);
  const int n0 = blockIdx.x * 32, k0 = blockIdx.y * 32;
  __shared__ float tile[32][33];
  const int tid = threadIdx.x;
  for (int idx = tid; idx < 1024; idx += 256) {
    int r = idx >> 5, c = idx & 31;
    tile[r][c] = in[(size_t)(k0 + r)*DIM + n0 + c];
  }
  __syncthreads();
  for (int idx = tid; idx < 1024; idx += 256) {
    int r = idx >> 5, c = idx & 31;
    out[(size_t)(n0 + r)*DIM + k0 + c] = f2bf(tile[c][r]);
  }
}

// ---------------- bf16 MFMA GEMM, C = A @ Bt^T  (Bt is N x K row-major) ----------------
template<int MODE>
__global__ __launch_bounds__(256)
void gemm_bt(const u16* __restrict__ A, const u16* __restrict__ W,
             u16* __restrict__ outb, float* __restrict__ outf) {
  __shared__ u16 lA[128*32];
  __shared__ u16 lB[128*32];
  const int tid  = threadIdx.x;
  const int wave = tid >> 6, lane = tid & 63;
  const int wm = wave >> 1, wn = wave & 1;
  const int lr = lane & 15, g = lane >> 4;

  const int m0 = blockIdx.x * 128;
  int sel, ny;
  const u16* Bt;
  if (MODE == 0) { sel = blockIdx.y >> 3; ny = blockIdx.y & 7; Bt = W + (size_t)sel * (DIM*DIM); }
  else           { sel = 0;              ny = blockIdx.y;      Bt = W; }
  const int n0 = ny * 128;

  facc4 acc[4][4] = {};

  for (int kt = 0; kt < DIM; kt += 32) {
    #pragma unroll
    for (int c = 0; c < 2; ++c) {
      const int slot = c*256 + wave*64 + lane;
      const int row  = slot >> 2, cg = slot & 3;
      const int col  = ((cg ^ (row & 3)) << 3);
      gload_lds16(A  + (size_t)(m0 + row)*DIM + kt + col, &lA[(c*256 + wave*64)*8]);
      gload_lds16(Bt + (size_t)(n0 + row)*DIM + kt + col, &lB[(c*256 + wave*64)*8]);
    }
    __syncthreads();
    bfrag8 af[4], bf[4];
    #pragma unroll
    for (int i = 0; i < 4; ++i) {
      const int ar = wm*64 + i*16 + lr;
      af[i] = *(const bfrag8*)&lA[ar*32 + ((g ^ (ar & 3)) << 3)];
      const int br = wn*64 + i*16 + lr;
      bf[i] = *(const bfrag8*)&lB[br*32 + ((g ^ (br & 3)) << 3)];
    }
    #pragma unroll
    for (int i = 0; i < 4; ++i)
      #pragma unroll
      for (int j = 0; j < 4; ++j)
        acc[i][j] = __builtin_amdgcn_mfma_f32_16x16x32_bf16(af[i], bf[j], acc[i][j], 0, 0, 0);
    __syncthreads();
  }

  const bool doElu = (MODE == 0) && (sel < 2);
  #pragma unroll
  for (int i = 0; i < 4; ++i) {
    #pragma unroll
    for (int j = 0; j < 4; ++j) {
      #pragma unroll
      for (int r = 0; r < 4; ++r) {
        const int gm = m0 + wm*64 + i*16 + g*4 + r;
        const int gn = n0 + wn*64 + j*16 + lr;
        float v = acc[i][j][r];
        if (MODE == 0) {
          if (doElu) v = (v > 0.f) ? (v + 1.f) : __expf(v);
          outb[(size_t)sel*((size_t)MROWS*DIM) + (size_t)gm*DIM + gn] = f2bf(v);
        } else {
          outf[(size_t)gm*DIM + gn] = v;
        }
      }
    }
  }
}

// ---------------- chunked causal linear-attention scan (MFMA) ----------------
// Ast layout: per (bh, chunk), 64x64 bf16 [e][d] = (K^T V)^T, i.e. Ast[e*64+d] = sum_t K[t][d] V[t][e]

// Phase A: per (b,h,chunk): Ast = (K^T V)^T in bf16, ksum = sum_t k (fp32)
__global__ __launch_bounds__(256) void phaseA(const u16* __restrict__ Kb, const u16* __restrict__ Vb,
                                              u16* __restrict__ Ast, float* __restrict__ ksum) {
  const int c = blockIdx.x, bh = blockIdx.y;
  const int b = bh >> 4, h = bh & 15;
  const int tid = threadIdx.x;
  const int wave = tid >> 6, lane = tid & 63, lr = lane & 15, g = lane >> 4;
  __shared__ u16 lKt[64*TS];   // lKt[d][t] = K[t][d]
  __shared__ u16 lVt[64*TS];   // lVt[e][t] = V[t][e]
  const size_t mbase = (size_t)b*SEQ + (size_t)c*CHUNK;

  for (int s = tid; s < 512; s += 256) {
    const int t = s >> 3, dg = (s & 7) * 8;
    const bfrag8 kk = *(const bfrag8*)&Kb[(mbase + t)*DIM + h*64 + dg];
    const bfrag8 vv = *(const bfrag8*)&Vb[(mbase + t)*DIM + h*64 + dg];
    #pragma unroll
    for (int j = 0; j < 8; ++j) {
      lKt[(dg + j)*TS + t] = (u16)kk[j];
      lVt[(dg + j)*TS + t] = (u16)vv[j];
    }
  }
  __syncthreads();

  // C'[e][d] = sum_t Vt[e][t] * Kt[d][t]; wave owns e-rows wave*16..+15
  facc4 acc[4] = {};
  #pragma unroll
  for (int kt = 0; kt < 2; ++kt) {
    const bfrag8 af = *(const bfrag8*)&lVt[(wave*16 + lr)*TS + kt*32 + g*8];
    #pragma unroll
    for (int j = 0; j < 4; ++j) {
      const bfrag8 bk = *(const bfrag8*)&lKt[(j*16 + lr)*TS + kt*32 + g*8];
      acc[j] = __builtin_amdgcn_mfma_f32_16x16x32_bf16(af, bk, acc[j], 0, 0, 0);
    }
  }
  u16* dst = Ast + (((size_t)bh*NCHUNK + c) << 12);
  #pragma unroll
  for (int j = 0; j < 4; ++j)
    #pragma unroll
    for (int r = 0; r < 4; ++r)
      dst[(wave*16 + g*4 + r)*64 + j*16 + lr] = f2bf(acc[j][r]);

  // ksum[d] = sum over row d of lKt
  const int d = tid >> 2, seg = tid & 3;
  const bfrag8 k0 = *(const bfrag8*)&lKt[d*TS + seg*16];
  const bfrag8 k1 = *(const bfrag8*)&lKt[d*TS + seg*16 + 8];
  float s = 0.f;
  #pragma unroll
  for (int j = 0; j < 8; ++j) s += bf2f((u16)k0[j]) + bf2f((u16)k1[j]);
  s += __shfl_xor(s, 1, 64);
  s += __shfl_xor(s, 2, 64);
  if (seg == 0) ksum[((size_t)bh*NCHUNK + c)*64 + d] = s;
}

// Phase B: in-place EXCLUSIVE prefix over chunks (fp32 accumulate, bf16 storage)
__global__ __launch_bounds__(256) void phaseB(u16* __restrict__ Ast, float* __restrict__ ksum) {
  const int bh = blockIdx.x, slice = blockIdx.y;
  const int tid = threadIdx.x;
  u16* base = Ast + (size_t)bh*NCHUNK*4096 + slice*256 + tid;
  float v[NCHUNK];
  #pragma unroll
  for (int c = 0; c < NCHUNK; ++c) v[c] = bf2f(base[(size_t)c*4096]);
  float run = 0.f;
  #pragma unroll
  for (int c = 0; c < NCHUNK; ++c) { base[(size_t)c*4096] = f2bf(run); run += v[c]; }
  if (slice == 0 && tid < 64) {
    float rs = 0.f;
    float* kp = ksum + (size_t)bh*NCHUNK*64 + tid;
    for (int c = 0; c < NCHUNK; ++c) { const float t = kp[c*64]; kp[c*64] = rs; rs += t; }
  }
}

// Phase C: out = (mask(QK^T)@V + Q@KV_prefix) / (rowsum(mask(QK^T)) + Q.ksum_prefix + eps)
__global__ __launch_bounds__(256) void phaseC(const u16* __restrict__ Qb, const u16* __restrict__ Kb,
                                              const u16* __restrict__ Vb, const u16* __restrict__ Ast,
                                              const float* __restrict__ ksum, u16* __restrict__ Ob) {
  const int c = blockIdx.x, bh = blockIdx.y;
  const int b = bh >> 4, h = bh & 15;
  const int tid = threadIdx.x;
  const int wave = tid >> 6, lane = tid & 63, lr = lane & 15, g = lane >> 4;
  __shared__ u16 lS  [64*TS];   // masked S, bf16, [rr][cc]
  __shared__ u16 lVt [64*TS];   // lVt[e][cc] = V[cc][e]
  __shared__ u16 lKVt[64*TS];   // lKVt[e][d] = KV_prefix[d][e]  (Ast layout, direct copy)
  __shared__ float lks[64];
  __shared__ float lrs[64];
  __shared__ float lqk[64];
  const size_t mbase = (size_t)b*SEQ + (size_t)c*CHUNK;

  // V transpose into LDS
  for (int s = tid; s < 512; s += 256) {
    const int t = s >> 3, dg = (s & 7) * 8;
    const bfrag8 vv = *(const bfrag8*)&Vb[(mbase + t)*DIM + h*64 + dg];
    #pragma unroll
    for (int j = 0; j < 8; ++j) lVt[(dg + j)*TS + t] = (u16)vv[j];
  }
  // KV prefix: already [e][d] bf16 — straight vector copy
  const u16* kvsrc = Ast + (((size_t)bh*NCHUNK + c) << 12);
  for (int s = tid; s < 512; s += 256) {
    const int e = s >> 3, dg = (s & 7) * 8;
    *(bfrag8*)&lKVt[e*TS + dg] = *(const bfrag8*)&kvsrc[e*64 + dg];
  }
  if (tid < 64) lks[tid] = ksum[((size_t)bh*NCHUNK + c)*64 + tid];

  // Q, K fragments straight from global (L1 serves cross-wave duplication)
  bfrag8 qf[2], kf[4][2];
  {
    const u16* qrow = Qb + (mbase + wave*16 + lr)*DIM + h*64;
    qf[0] = *(const bfrag8*)&qrow[g*8];
    qf[1] = *(const bfrag8*)&qrow[32 + g*8];
  }
  #pragma unroll
  for (int j = 0; j < 4; ++j) {
    const u16* krow = Kb + (mbase + j*16 + lr)*DIM + h*64;
    kf[j][0] = *(const bfrag8*)&krow[g*8];
    kf[j][1] = *(const bfrag8*)&krow[32 + g*8];
  }

  // S = Q K^T (fp32 acc), mask, rowsum, bf16 into LDS
  facc4 accs[4] = {};
  #pragma unroll
  for (int kt = 0; kt < 2; ++kt)
    #pragma unroll
    for (int j = 0; j < 4; ++j)
      accs[j] = __builtin_amdgcn_mfma_f32_16x16x32_bf16(qf[kt], kf[j][kt], accs[j], 0, 0, 0);

  float rs[4] = {0.f, 0.f, 0.f, 0.f};
  #pragma unroll
  for (int j = 0; j < 4; ++j) {
    const int cc = j*16 + lr;
    #pragma unroll
    for (int r = 0; r < 4; ++r) {
      const int rr = wave*16 + g*4 + r;
      const float vS = (cc <= rr) ? accs[j][r] : 0.f;
      rs[r] += vS;
      lS[rr*TS + cc] = f2bf(vS);
    }
  }
  #pragma unroll
  for (int r = 0; r < 4; ++r) {
    float t = rs[r];
    t += __shfl_xor(t, 1, 64); t += __shfl_xor(t, 2, 64);
    t += __shfl_xor(t, 4, 64); t += __shfl_xor(t, 8, 64);
    if (lr == 0) lrs[wave*16 + g*4 + r] = t;
  }
  __syncthreads();

  // den part 2: Q . ksum_prefix  (row = wave*16+lr, 16-elem segment per g)
  {
    const u16* qr2 = Qb + (mbase + wave*16 + lr)*DIM + h*64 + g*16;
    const bfrag8 a0 = *(const bfrag8*)&qr2[0];
    const bfrag8 a1 = *(const bfrag8*)&qr2[8];
    float t = 0.f;
    #pragma unroll
    for (int j = 0; j < 8; ++j)
      t += bf2f((u16)a0[j]) * lks[g*16 + j] + bf2f((u16)a1[j]) * lks[g*16 + 8 + j];
    t += __shfl_xor(t, 16, 64);
    t += __shfl_xor(t, 32, 64);
    if (g == 0) lqk[wave*16 + lr] = t;
  }

  // num = S@V + Q@KV_prefix
  facc4 acco[4] = {};
  #pragma unroll
  for (int kt = 0; kt < 2; ++kt) {
    const bfrag8 sf = *(const bfrag8*)&lS[(wave*16 + lr)*TS + kt*32 + g*8];
    #pragma unroll
    for (int j = 0; j < 4; ++j) {
      const bfrag8 vf = *(const bfrag8*)&lVt[(j*16 + lr)*TS + kt*32 + g*8];
      acco[j] = __builtin_amdgcn_mfma_f32_16x16x32_bf16(sf, vf, acco[j], 0, 0, 0);
    }
  }
  #pragma unroll
  for (int kt = 0; kt < 2; ++kt)
    #pragma unroll
    for (int j = 0; j < 4; ++j) {
      const bfrag8 kvf = *(const bfrag8*)&lKVt[(j*16 + lr)*TS + kt*32 + g*8];
      acco[j] = __builtin_amdgcn_mfma_f32_16x16x32_bf16(qf[kt], kvf, acco[j], 0, 0, 0);
    }

  #pragma unroll
  for (int r = 0; r < 4; ++r) {
    const int rr = wave*16 + g*4 + r;
    const float rden = 1.0f / (lrs[rr] + lqk[rr] + 1e-6f);
    #pragma unroll
    for (int j = 0; j < 4; ++j)
      Ob[(mbase + rr)*DIM + h*64 + j*16 + lr] = f2bf(acco[j][r] * rden);
  }
}

// ---------------- launch ----------------
extern "C" void kernel_launch(void* const* d_in, const int* in_sizes, int n_in,
                              void* d_out, int out_size, void* d_ws, size_t ws_size,
                              hipStream_t stream) {
  const float* x    = (const float*)d_in[0];
  const float* Wq   = (const float*)d_in[1];
  const float* Wk   = (const float*)d_in[2];
  const float* Wv   = (const float*)d_in[3];
  const float* Wo   = (const float*)d_in[4];
  const float* proj = (const float*)d_in[5];
  float* out = (float*)d_out;

  char* ws = (char*)d_ws;
  u16*   xb   = (u16*)  (ws);                       // 16 MB : x in bf16
  u16*   wt   = (u16*)  (ws + 16777216);            //  8 MB : Wq',Wk',Wv^T,Wo^T bf16 (transposed)
  u16*   qkv  = (u16*)  (ws + 25165824);            // 48 MB : Q,K,V bf16 (post feature map)
  u16*   Ob   = (u16*)  (ws + 75497472);            // 16 MB : attention out bf16
  u16*   Ast  = (u16*)  (ws + 92274688);            // 16 MB : chunk KV states bf16 [e][d]
  float* ksum = (float*)(ws + 109051904);           // 512 KB : chunk k-sums fp32
  (void)ws_size; (void)in_sizes; (void)n_in; (void)out_size;

  conv_f32_bf16<<<dim3((MROWS*DIM)/1024), 256, 0, stream>>>(x, xb);
  fold_qk      <<<dim3(DIM/32, NH, 2), 256, 0, stream>>>(Wq, Wk, proj, wt);
  trans_conv   <<<dim3(DIM/32, DIM/32, 2), 256, 0, stream>>>(Wv, Wo, wt);

  gemm_bt<0><<<dim3(MROWS/128, 24), 256, 0, stream>>>(xb, wt, qkv, nullptr);

  const u16* Qb = qkv;
  const u16* Kb = qkv + (size_t)MROWS*DIM;
  const u16* Vb = qkv + 2*(size_t)MROWS*DIM;

  phaseA<<<dim3(NCHUNK, BH), 256, 0, stream>>>(Kb, Vb, Ast, ksum);
  phaseB<<<dim3(BH, 16), 256, 0, stream>>>(Ast, ksum);
  phaseC<<<dim3(NCHUNK, BH), 256, 0, stream>>>(Qb, Kb, Vb, Ast, ksum, Ob);

  gemm_bt<1><<<dim3(MROWS/128, 8), 256, 0, stream>>>(Ob, wt + 3*(size_t)DIM*DIM, nullptr, out);
}